// Round 2
// baseline (1494.712 us; speedup 1.0000x reference)
//
#include <hip/hip_runtime.h>
#include <cstdint>
#include <cstddef>

#define NB 8
#define SL 1024
#define ED 1024
#define NH 16
#define DKH 64

typedef __attribute__((ext_vector_type(4))) float f32x4;
typedef __attribute__((ext_vector_type(8))) short short8;

__device__ __forceinline__ unsigned short bf16_rn(float x) {
    unsigned int u = __float_as_uint(x);
    u += 0x7FFFu + ((u >> 16) & 1u);
    return (unsigned short)(u >> 16);
}
__device__ __forceinline__ float bf16_f(unsigned short h) {
    return __uint_as_float(((unsigned int)h) << 16);
}
__device__ __forceinline__ void split2(float x, unsigned short& hi, unsigned short& lo) {
    unsigned short h = bf16_rn(x);
    hi = h;
    lo = bf16_rn(x - bf16_f(h));
}

// async global->LDS DMA, 16B per lane. LDS dest = wave-uniform base + lane*16 (linear).
__device__ __forceinline__ void dma16(const unsigned short* src, unsigned short* dst) {
    __builtin_amdgcn_global_load_lds(
        (const __attribute__((address_space(1))) void*)src,
        (__attribute__((address_space(3))) void*)dst,
        16, 0, 0);
}

// Stage ROWS x 32 ushort plane (row stride ld elems, origin r0/k0) into linear LDS [ROWS][32].
// Each instr moves 1KB = 16 rows; instrs split across 4 waves.
template<int ROWS>
__device__ __forceinline__ void dma_plane(
    const unsigned short* __restrict__ g, unsigned short* l,
    int ld, int r0, int k0, int wave, int lane)
{
    for (int i = wave; i < ROWS / 16; i += 4) {
        const unsigned short* src =
            g + (size_t)(r0 + i * 16 + (lane >> 2)) * ld + k0 + (lane & 3) * 8;
        dma16(src, l + i * 512);
    }
}

// -------- GEMM core: BM x BN tile, BK=32, 256 threads, double-buffered LDS + DMA --------
// A: APRE ? pre-split hi/lo planes row-major [m][k] (DMA) : fp32 row-major (reg-staged, split once).
// B: always pre-split hi/lo planes [n][k] row-major (DMA).
// LDS layout linear stride 32 shorts; fp32-A path chunk-swizzled (c ^= (row>>1)&3) both sides.
// Verified fragment layouts preserved: A[m=l16][k=quad*8+j], B[n=l16][k=quad*8+j],
// C col=l16, row=quad*4+r.
template<bool APRE, int BM, int BN, int WR, int WC, int ROWG, int COLT>
__device__ __forceinline__ void gemm_core3(
    unsigned short* smem,
    const float* __restrict__ Af,
    const unsigned short* __restrict__ Ahg, const unsigned short* __restrict__ Alg,
    int lda,
    const unsigned short* __restrict__ Bhg, const unsigned short* __restrict__ Blg,
    int ldb, int Kd, int m0, int n0,
    f32x4 (&acc)[ROWG][COLT])
{
    static_assert(WR * WC == 4, "4 waves");
    static_assert(16 * ROWG * WR == BM, "rows");
    static_assert(16 * COLT * WC == BN, "cols");
    static_assert(APRE || BM == 128, "fp32 staging assumes BM=128");

    constexpr int ASZ = BM * 32;
    constexpr int BSZ = BN * 32;
    unsigned short* Ah = smem;
    unsigned short* Al = smem + 2 * ASZ;
    unsigned short* Bh = smem + 4 * ASZ;
    unsigned short* Bl = smem + 4 * ASZ + 2 * BSZ;

    const int tid  = threadIdx.x;
    const int wave = tid >> 6;
    const int lane = tid & 63;
    const int quad = lane >> 4;
    const int l16  = lane & 15;
    const int wr   = wave / WC;
    const int wc   = wave % WC;

#pragma unroll
    for (int g = 0; g < ROWG; g++)
#pragma unroll
        for (int jt = 0; jt < COLT; jt++) acc[g][jt] = (f32x4)(0.0f);

    // fp32-A reg staging: thread owns row ar, 16 floats at col (tid&1)*16 (chunks acb, acb+1)
    const int ar  = tid >> 1;
    const int acb = (tid & 1) * 2;

    auto load_a = [&](int kk, float4 st[4]) {
        const float* p = Af + (size_t)(m0 + ar) * lda + kk + (tid & 1) * 16;
        st[0] = *(const float4*)(p + 0);
        st[1] = *(const float4*)(p + 4);
        st[2] = *(const float4*)(p + 8);
        st[3] = *(const float4*)(p + 12);
    };
    auto write_a = [&](int b, const float4 st[4]) {
        unsigned short* dh = Ah + b * ASZ;
        unsigned short* dl = Al + b * ASZ;
#pragma unroll
        for (int w = 0; w < 2; w++) {
            const int csw = (acb + w) ^ ((ar >> 1) & 3);   // write-side chunk swizzle
            const float4 u0 = st[2 * w], u1 = st[2 * w + 1];
            short8 h8, l8;
            unsigned short h, l;
            split2(u0.x, h, l); h8[0] = (short)h; l8[0] = (short)l;
            split2(u0.y, h, l); h8[1] = (short)h; l8[1] = (short)l;
            split2(u0.z, h, l); h8[2] = (short)h; l8[2] = (short)l;
            split2(u0.w, h, l); h8[3] = (short)h; l8[3] = (short)l;
            split2(u1.x, h, l); h8[4] = (short)h; l8[4] = (short)l;
            split2(u1.y, h, l); h8[5] = (short)h; l8[5] = (short)l;
            split2(u1.z, h, l); h8[6] = (short)h; l8[6] = (short)l;
            split2(u1.w, h, l); h8[7] = (short)h; l8[7] = (short)l;
            *(short8*)&dh[ar * 32 + csw * 8] = h8;
            *(short8*)&dl[ar * 32 + csw * 8] = l8;
        }
    };
    auto stage_b = [&](int b, int kk) {
        dma_plane<BN>(Bhg, Bh + b * BSZ, ldb, n0, kk, wave, lane);
        dma_plane<BN>(Blg, Bl + b * BSZ, ldb, n0, kk, wave, lane);
    };
    auto stage_a_dma = [&](int b, int kk) {
        dma_plane<BM>(Ahg, Ah + b * ASZ, lda, m0, kk, wave, lane);
        dma_plane<BM>(Alg, Al + b * ASZ, lda, m0, kk, wave, lane);
    };

    // ---- prologue: stage k0=0 into buf 0 ----
    if constexpr (APRE) {
        stage_a_dma(0, 0);
    } else {
        float4 st[4];
        load_a(0, st);
        write_a(0, st);
    }
    stage_b(0, 0);
    __syncthreads();   // drains vmcnt -> DMA complete

    int buf = 0;
    for (int k0 = 0; k0 < Kd; k0 += 32) {
        const int nk = k0 + 32;
        float4 st[4];
        // issue next tile's loads BEFORE compute (latency hides under MFMA)
        if (nk < Kd) {
            if constexpr (APRE) stage_a_dma(buf ^ 1, nk);
            else                load_a(nk, st);
            stage_b(buf ^ 1, nk);
        }
        // ---- compute current buffer ----
        const unsigned short* pAh = Ah + buf * ASZ;
        const unsigned short* pAl = Al + buf * ASZ;
        const unsigned short* pBh = Bh + buf * BSZ;
        const unsigned short* pBl = Bl + buf * BSZ;
        short8 ah[ROWG], al[ROWG];
#pragma unroll
        for (int g = 0; g < ROWG; g++) {
            const int row = wr * (16 * ROWG) + g * 16 + l16;
            int co;
            if constexpr (APRE) co = quad * 8;
            else                co = (quad ^ ((row >> 1) & 3)) * 8;   // read-side swizzle
            ah[g] = *(const short8*)&pAh[row * 32 + co];
            al[g] = *(const short8*)&pAl[row * 32 + co];
        }
#pragma unroll
        for (int jt = 0; jt < COLT; jt++) {
            const int brow = wc * (16 * COLT) + jt * 16 + l16;
            const short8 bh = *(const short8*)&pBh[brow * 32 + quad * 8];
            const short8 bl = *(const short8*)&pBl[brow * 32 + quad * 8];
#pragma unroll
            for (int g = 0; g < ROWG; g++) {
                acc[g][jt] = __builtin_amdgcn_mfma_f32_16x16x32_bf16(al[g], bh, acc[g][jt], 0, 0, 0);
                acc[g][jt] = __builtin_amdgcn_mfma_f32_16x16x32_bf16(ah[g], bl, acc[g][jt], 0, 0, 0);
                acc[g][jt] = __builtin_amdgcn_mfma_f32_16x16x32_bf16(ah[g], bh, acc[g][jt], 0, 0, 0);
            }
        }
        // fp32-A: split+write next tile after compute (global latency already elapsed)
        if constexpr (!APRE) {
            if (nk < Kd) write_a(buf ^ 1, st);
        }
        __syncthreads();
        buf ^= 1;
    }
}

// ---- weight transpose + split: W (E_in x E_out, [k][n]) -> WT hi/lo [n][k] ----
__global__ __launch_bounds__(256)
void k_wsplitT(const float* __restrict__ W,
               unsigned short* __restrict__ Th, unsigned short* __restrict__ Tl)
{
    __shared__ float tile[64 * 65];
    const int n0 = blockIdx.x * 64;
    const int k0 = blockIdx.y * 64;
    const int tid = threadIdx.x;
    for (int i = tid; i < 64 * 64; i += 256) {
        const int rk = i >> 6, cn = i & 63;
        tile[rk * 65 + cn] = W[(size_t)(k0 + rk) * ED + n0 + cn];
    }
    __syncthreads();
    for (int i = tid; i < 64 * 64; i += 256) {
        const int rn = i >> 6, ck = i & 63;
        unsigned short h, l;
        split2(tile[ck * 65 + rn], h, l);
        Th[(size_t)(n0 + rn) * ED + k0 + ck] = h;
        Tl[(size_t)(n0 + rn) * ED + k0 + ck] = l;
    }
}

// ---- q/k projection: 128x128 tile, writes pre-split heads layout [n,h,s,d] hi/lo ----
__global__ __launch_bounds__(256)
void k_projQK(const float* __restrict__ X,
              const unsigned short* __restrict__ Wh, const unsigned short* __restrict__ Wl,
              const float* __restrict__ bias,
              unsigned short* __restrict__ Oh, unsigned short* __restrict__ Ol)
{
    __shared__ unsigned short smem[(128 + 128) * 128];
    const int m0 = blockIdx.x * 128;
    const int n0 = blockIdx.y * 128;
    f32x4 acc[4][4];
    gemm_core3<false, 128, 128, 2, 2, 4, 4>(smem, X, nullptr, nullptr, ED,
                                            Wh, Wl, ED, ED, m0, n0, acc);

    const int tid = threadIdx.x, wave = tid >> 6, lane = tid & 63;
    const int quad = lane >> 4, l16 = lane & 15;
    const int wr = wave >> 1, wc = wave & 1;
#pragma unroll
    for (int jt = 0; jt < 4; jt++) {
        const int col = n0 + wc * 64 + jt * 16 + l16;
        const int h = col >> 6, d = col & 63;
        const float b = bias[col];
#pragma unroll
        for (int g = 0; g < 4; g++) {
#pragma unroll
            for (int rr = 0; rr < 4; rr++) {
                const int m = m0 + wr * 64 + g * 16 + quad * 4 + rr;
                const int n = m >> 10, s = m & 1023;
                const size_t idx = (((size_t)(n * NH + h)) * SL + s) * DKH + d;
                unsigned short hh, ll;
                split2(acc[g][jt][rr] + b, hh, ll);
                Oh[idx] = hh;
                Ol[idx] = ll;
            }
        }
    }
}

// ---- v projection: 128x64 tile, writes pre-split TRANSPOSED vT[ghead][d][s] hi/lo ----
__global__ __launch_bounds__(256)
void k_projV(const float* __restrict__ X,
             const unsigned short* __restrict__ Wh, const unsigned short* __restrict__ Wl,
             const float* __restrict__ bias,
             unsigned short* __restrict__ Th, unsigned short* __restrict__ Tl)
{
    __shared__ unsigned short smem[(128 + 64) * 128];   // 48KB; reused as T (33KB)
    const int m0 = blockIdx.x * 128;
    const int n0 = blockIdx.y * 64;
    f32x4 acc[2][4];
    gemm_core3<false, 128, 64, 4, 1, 2, 4>(smem, X, nullptr, nullptr, ED,
                                           Wh, Wl, ED, ED, m0, n0, acc);

    // core ended with __syncthreads(): smem reusable
    unsigned int* T = (unsigned int*)smem;   // [128][65] packed (hi | lo<<16), [s_local][d]
    const int tid = threadIdx.x, wave = tid >> 6, lane = tid & 63;
    const int quad = lane >> 4, l16 = lane & 15;
#pragma unroll
    for (int jt = 0; jt < 4; jt++) {
        const int d = jt * 16 + l16;
        const float b = bias[n0 + d];
#pragma unroll
        for (int g = 0; g < 2; g++) {
#pragma unroll
            for (int rr = 0; rr < 4; rr++) {
                const int sl = wave * 32 + g * 16 + quad * 4 + rr;
                unsigned short hh, ll;
                split2(acc[g][jt][rr] + b, hh, ll);
                T[sl * 65 + d] = (unsigned int)hh | ((unsigned int)ll << 16);
            }
        }
    }
    __syncthreads();
    const int d  = tid >> 2;            // 0..63
    const int sc = (tid & 3) * 32;      // 0,32,64,96
    const int ghead = (m0 >> 10) * NH + (n0 >> 6);
    const size_t rowbase = ((size_t)ghead * DKH + d) * SL + (m0 & 1023) + sc;
#pragma unroll
    for (int c = 0; c < 4; c++) {
        short8 h8, l8;
#pragma unroll
        for (int i = 0; i < 8; i++) {
            const unsigned int u = T[(sc + c * 8 + i) * 65 + d];
            h8[i] = (short)(u & 0xFFFFu);
            l8[i] = (short)(u >> 16);
        }
        *(short8*)(Th + rowbase + c * 8) = h8;
        *(short8*)(Tl + rowbase + c * 8) = l8;
    }
}

// ---- logits: 128x128 tile, attn[head][s][t] = (qh @ kh^T)/8, masked; both operands DMA ----
__global__ __launch_bounds__(256)
void k_logits(const unsigned short* __restrict__ qh_h, const unsigned short* __restrict__ qh_l,
              const unsigned short* __restrict__ kh_h, const unsigned short* __restrict__ kh_l,
              const int* __restrict__ mask, float* __restrict__ attn)
{
    __shared__ unsigned short smem[(128 + 128) * 128];
    const int head = blockIdx.z;
    const int n = head >> 4;
    const int m0 = blockIdx.x * 128;
    const int n0 = blockIdx.y * 128;
    const size_t hb = (size_t)head * SL * DKH;
    f32x4 acc[4][4];
    gemm_core3<true, 128, 128, 2, 2, 4, 4>(smem, nullptr, qh_h + hb, qh_l + hb, DKH,
                                           kh_h + hb, kh_l + hb, DKH, DKH, m0, n0, acc);

    const int tid = threadIdx.x, wave = tid >> 6, lane = tid & 63;
    const int quad = lane >> 4, l16 = lane & 15;
    const int wr = wave >> 1, wc = wave & 1;
    const float scale = 0.125f;  // 1/sqrt(64)
#pragma unroll
    for (int jt = 0; jt < 4; jt++) {
        const int t = n0 + wc * 64 + jt * 16 + l16;
#pragma unroll
        for (int g = 0; g < 4; g++) {
#pragma unroll
            for (int rr = 0; rr < 4; rr++) {
                const int s = m0 + wr * 64 + g * 16 + quad * 4 + rr;
                float vv = acc[g][jt][rr] * scale;
                if (mask[((size_t)n * SL + s) * SL + t]) vv = -1e9f;
                attn[((size_t)head * SL + s) * SL + t] = vv;
            }
        }
    }
}

// ---- row softmax in place: one wave per row, shuffle-only reductions ----
__global__ __launch_bounds__(256)
void k_softmax(float* __restrict__ attn)
{
    const int tid = threadIdx.x;
    const int wave = tid >> 6, lane = tid & 63;
    const size_t row = (size_t)blockIdx.x * 4 + wave;
    float* p = attn + row * SL;

    float4 v[4];
    float mx = -3.4e38f;
#pragma unroll
    for (int i = 0; i < 4; i++) {
        v[i] = *(const float4*)(p + lane * 4 + i * 256);
        mx = fmaxf(mx, fmaxf(fmaxf(v[i].x, v[i].y), fmaxf(v[i].z, v[i].w)));
    }
#pragma unroll
    for (int o = 32; o > 0; o >>= 1) mx = fmaxf(mx, __shfl_xor(mx, o));

    float sum = 0.0f;
#pragma unroll
    for (int i = 0; i < 4; i++) {
        v[i].x = __expf(v[i].x - mx);
        v[i].y = __expf(v[i].y - mx);
        v[i].z = __expf(v[i].z - mx);
        v[i].w = __expf(v[i].w - mx);
        sum += v[i].x + v[i].y + v[i].z + v[i].w;
    }
#pragma unroll
    for (int o = 32; o > 0; o >>= 1) sum += __shfl_xor(sum, o);

    const float inv = 1.0f / sum;
#pragma unroll
    for (int i = 0; i < 4; i++) {
        v[i].x *= inv; v[i].y *= inv; v[i].z *= inv; v[i].w *= inv;
        *(float4*)(p + lane * 4 + i * 256) = v[i];
    }
}

// ---- PV: 128x64 tile, oh[n][s][h*64+d] = P @ V; V pre-split transposed; writes oh pre-split ----
__global__ __launch_bounds__(256)
void k_pv(const float* __restrict__ attn,
          const unsigned short* __restrict__ vTh, const unsigned short* __restrict__ vTl,
          unsigned short* __restrict__ Oh, unsigned short* __restrict__ Ol)
{
    __shared__ unsigned short smem[(128 + 64) * 128];
    const int head = blockIdx.z;
    const int m0 = blockIdx.x * 128;
    const float* P = attn + (size_t)head * SL * SL;
    const unsigned short* Bh = vTh + (size_t)head * DKH * SL;
    const unsigned short* Bl = vTl + (size_t)head * DKH * SL;
    f32x4 acc[2][4];
    gemm_core3<false, 128, 64, 4, 1, 2, 4>(smem, P, nullptr, nullptr, SL,
                                           Bh, Bl, SL, SL, m0, 0, acc);

    const int tid = threadIdx.x, wave = tid >> 6, lane = tid & 63;
    const int quad = lane >> 4, l16 = lane & 15;
    const int n = head >> 4, h = head & 15;
#pragma unroll
    for (int jt = 0; jt < 4; jt++) {
        const int d = jt * 16 + l16;
#pragma unroll
        for (int g = 0; g < 2; g++) {
#pragma unroll
            for (int rr = 0; rr < 4; rr++) {
                const int s = m0 + wave * 32 + g * 16 + quad * 4 + rr;
                const size_t idx = ((size_t)n * SL + s) * ED + h * DKH + d;
                unsigned short hh, ll;
                split2(acc[g][jt][rr], hh, ll);
                Oh[idx] = hh;
                Ol[idx] = ll;
            }
        }
    }
}

// ---- output projection: 128x128 tile, both operands DMA; out = oh @ wo + bo ----
__global__ __launch_bounds__(256)
void k_outproj(const unsigned short* __restrict__ Ah, const unsigned short* __restrict__ Al,
               const unsigned short* __restrict__ Wh, const unsigned short* __restrict__ Wl,
               const float* __restrict__ bias, float* __restrict__ out)
{
    __shared__ unsigned short smem[(128 + 128) * 128];
    const int m0 = blockIdx.x * 128;
    const int n0 = blockIdx.y * 128;
    f32x4 acc[4][4];
    gemm_core3<true, 128, 128, 2, 2, 4, 4>(smem, nullptr, Ah, Al, ED,
                                           Wh, Wl, ED, ED, m0, n0, acc);

    const int tid = threadIdx.x, wave = tid >> 6, lane = tid & 63;
    const int quad = lane >> 4, l16 = lane & 15;
    const int wr = wave >> 1, wc = wave & 1;
#pragma unroll
    for (int jt = 0; jt < 4; jt++) {
        const int col = n0 + wc * 64 + jt * 16 + l16;
        const float b = bias[col];
#pragma unroll
        for (int g = 0; g < 4; g++) {
#pragma unroll
            for (int rr = 0; rr < 4; rr++) {
                const int m = m0 + wr * 64 + g * 16 + quad * 4 + rr;
                out[(size_t)m * ED + col] = acc[g][jt][rr] + b;
            }
        }
    }
}

extern "C" void kernel_launch(void* const* d_in, const int* in_sizes, int n_in,
                              void* d_out, int out_size, void* d_ws, size_t ws_size,
                              hipStream_t stream) {
    const float* q    = (const float*)d_in[0];
    const float* k    = (const float*)d_in[1];
    const float* v    = (const float*)d_in[2];
    const int*   mask = (const int*)d_in[3];
    const float* wq = (const float*)d_in[4];
    const float* bq = (const float*)d_in[5];
    const float* wk = (const float*)d_in[6];
    const float* bk = (const float*)d_in[7];
    const float* wv = (const float*)d_in[8];
    const float* bv = (const float*)d_in[9];
    const float* wo = (const float*)d_in[10];
    const float* bo = (const float*)d_in[11];

    float* out  = (float*)d_out;
    float* attn = out + (size_t)NB * SL * ED;   // second output: (N,H,S,S)

    // ---- workspace map (ushort planes), total 117.4 MB ----
    unsigned short* w = (unsigned short*)d_ws;
    const size_t WPL = (size_t)ED * ED;
    unsigned short* wqT_h = w + 0 * WPL;
    unsigned short* wqT_l = w + 1 * WPL;
    unsigned short* wkT_h = w + 2 * WPL;
    unsigned short* wkT_l = w + 3 * WPL;
    unsigned short* wvT_h = w + 4 * WPL;
    unsigned short* wvT_l = w + 5 * WPL;
    unsigned short* woT_h = w + 6 * WPL;
    unsigned short* woT_l = w + 7 * WPL;
    unsigned short* base  = w + 8 * WPL;
    const size_t HPL = (size_t)NB * NH * SL * DKH;
    unsigned short* qh_h = base + 0 * HPL;
    unsigned short* qh_l = base + 1 * HPL;
    unsigned short* kh_h = base + 2 * HPL;
    unsigned short* kh_l = base + 3 * HPL;
    unsigned short* vT_h = base + 4 * HPL;
    unsigned short* vT_l = base + 5 * HPL;
    unsigned short* oh_h = qh_h;   // reuse: qh dead after k_logits
    unsigned short* oh_l = qh_l;

    const dim3 blk(256);
    const dim3 gw(ED / 64, ED / 64);
    hipLaunchKernelGGL(k_wsplitT, gw, blk, 0, stream, wq, wqT_h, wqT_l);
    hipLaunchKernelGGL(k_wsplitT, gw, blk, 0, stream, wk, wkT_h, wkT_l);
    hipLaunchKernelGGL(k_wsplitT, gw, blk, 0, stream, wv, wvT_h, wvT_l);
    hipLaunchKernelGGL(k_wsplitT, gw, blk, 0, stream, wo, woT_h, woT_l);

    const dim3 gproj(8192 / 128, ED / 128);     // (64, 8)
    hipLaunchKernelGGL(k_projQK, gproj, blk, 0, stream, q, wqT_h, wqT_l, bq, qh_h, qh_l);
    hipLaunchKernelGGL(k_projQK, gproj, blk, 0, stream, k, wkT_h, wkT_l, bk, kh_h, kh_l);

    const dim3 gprojV(8192 / 128, ED / 64);     // (64, 16)
    hipLaunchKernelGGL(k_projV, gprojV, blk, 0, stream, v, wvT_h, wvT_l, bv, vT_h, vT_l);

    const dim3 glog(SL / 128, SL / 128, NB * NH);   // (8, 8, 128)
    hipLaunchKernelGGL(k_logits, glog, blk, 0, stream, qh_h, qh_l, kh_h, kh_l, mask, attn);

    hipLaunchKernelGGL(k_softmax, dim3(NB * NH * SL / 4), blk, 0, stream, attn);

    const dim3 gpv(SL / 128, 1, NB * NH);           // (8, 1, 128)
    hipLaunchKernelGGL(k_pv, gpv, blk, 0, stream, attn, vT_h, vT_l, oh_h, oh_l);

    hipLaunchKernelGGL(k_outproj, gproj, blk, 0, stream, oh_h, oh_l, woT_h, woT_l, bo, out);
}